// Round 26
// baseline (497.203 us; speedup 1.0000x reference)
//
#include <hip/hip_runtime.h>
#include <math.h>

// ---- problem constants ----
#define NTOK    4096      // B*S
#define DMODEL  512
#define NEXP    32
#define RRANK   64
#define HEXP    512
#define HSHARED 4096
#define SEQ     1024
#define BATCH   4
#define NHEAD   8
#define TOPK    4
#define NLAYER  2
#define QBLK    64
#define KBLK    64
#define MAXTILE 160       // max padded expert m-tiles: 16384/128 + 32
#define DDU     262144    // 512*512

typedef __attribute__((ext_vector_type(8))) short bf16x8;
typedef __attribute__((ext_vector_type(4))) float f32x4;

// gelu_tanh(x) == x * sigmoid(2*0.7978845608*(x + 0.044715 x^3)); one v_exp + rcp
__device__ __forceinline__ float gelu_f(float x) {
    float u = 1.5957691216057308f * (x + 0.044715f * x * x * x);
    return x * __builtin_amdgcn_rcpf(1.f + __expf(-u));
}
__device__ __forceinline__ unsigned short f2bf(float f) {
    unsigned int u = __float_as_uint(f);
    u += 0x7FFFu + ((u >> 16) & 1u);
    return (unsigned short)(u >> 16);
}
__device__ __forceinline__ float bf2f(unsigned short u) {
    return __uint_as_float((unsigned int)u << 16);
}
// async global->LDS, 16B per lane; LDS dest wave-uniform base + lane*16
__device__ __forceinline__ void gl_lds16(const void* g, void* l) {
    __builtin_amdgcn_global_load_lds(
        (const __attribute__((address_space(1))) void*)g,
        (__attribute__((address_space(3))) void*)l, 16, 0, 0);
}

// ---------------- LayerNorm body (bf16 out), rowblk covers 4 rows ----------------
__device__ __forceinline__ void ln_body(const float* x, const float* s, const float* b,
                                        unsigned short* outb, int rowblk) {
    int wave = threadIdx.x >> 6, lane = threadIdx.x & 63;
    int row = rowblk * 4 + wave;
    const float* xr = x + (size_t)row * DMODEL;
    float v[8];
    float sum = 0.f;
#pragma unroll
    for (int i = 0; i < 8; i++) { v[i] = xr[lane + i * 64]; sum += v[i]; }
#pragma unroll
    for (int o = 32; o; o >>= 1) sum += __shfl_xor(sum, o);
    float m = sum * (1.f / DMODEL);
    float vs = 0.f;
#pragma unroll
    for (int i = 0; i < 8; i++) { float d = v[i] - m; vs += d * d; }
#pragma unroll
    for (int o = 32; o; o >>= 1) vs += __shfl_xor(vs, o);
    float rstd = rsqrtf(vs * (1.f / DMODEL) + 1e-5f);
#pragma unroll
    for (int i = 0; i < 8; i++) {
        int c = lane + i * 64;
        outb[(size_t)row * DMODEL + c] = f2bf((v[i] - m) * rstd * s[c] + b[c]);
    }
}

// ---------------- fused split-K reduce (+bias +residual +MoE) + LayerNorm (+router scores) ----------------
template <int SK, bool MOE, int MODE, bool ROUTER = false>
__global__ __launch_bounds__(256) void reduceln_kernel(
    const float* __restrict__ pbuf, const float* __restrict__ bias,
    const unsigned short* __restrict__ eogb, const float* __restrict__ topw,
    const int* __restrict__ pos, float* __restrict__ xb,
    const float* __restrict__ s, const float* __restrict__ b,
    float* __restrict__ outf, unsigned short* __restrict__ outb,
    const float* __restrict__ rdru, float* __restrict__ rsc) {
    int wave = threadIdx.x >> 6, lane = threadIdx.x & 63;
    int row = blockIdx.x * 4 + wave;
    int cb = lane * 8;
    size_t base = (size_t)row * DMODEL + cb;
    float v[8];
    {
        float4 a0 = *(const float4*)(xb + base);
        float4 a1 = *(const float4*)(xb + base + 4);
        float4 b0 = *(const float4*)(bias + cb);
        float4 b1 = *(const float4*)(bias + cb + 4);
        v[0] = a0.x + b0.x; v[1] = a0.y + b0.y; v[2] = a0.z + b0.z; v[3] = a0.w + b0.w;
        v[4] = a1.x + b1.x; v[5] = a1.y + b1.y; v[6] = a1.z + b1.z; v[7] = a1.w + b1.w;
    }
#pragma unroll
    for (int sk = 0; sk < SK; sk++) {
        const float* p = pbuf + (size_t)sk * NTOK * DMODEL + base;
        float4 p0 = *(const float4*)p;
        float4 p1 = *(const float4*)(p + 4);
        v[0] += p0.x; v[1] += p0.y; v[2] += p0.z; v[3] += p0.w;
        v[4] += p1.x; v[5] += p1.y; v[6] += p1.z; v[7] += p1.w;
    }
    if (MOE) {
#pragma unroll
        for (int k = 0; k < TOPK; k++) {
            float w = topw[row * TOPK + k];
            bf16x8 e = *(const bf16x8*)(eogb + (size_t)pos[row * TOPK + k] * DMODEL + cb);
#pragma unroll
            for (int i = 0; i < 8; i++) v[i] += w * bf2f((unsigned short)e[i]);
        }
    }
    *(float4*)(xb + base) = make_float4(v[0], v[1], v[2], v[3]);
    *(float4*)(xb + base + 4) = make_float4(v[4], v[5], v[6], v[7]);
    float sum = 0.f;
#pragma unroll
    for (int i = 0; i < 8; i++) sum += v[i];
#pragma unroll
    for (int o = 32; o; o >>= 1) sum += __shfl_xor(sum, o);
    float m = sum * (1.f / DMODEL);
    float vs = 0.f;
#pragma unroll
    for (int i = 0; i < 8; i++) { float d = v[i] - m; vs += d * d; }
#pragma unroll
    for (int o = 32; o; o >>= 1) vs += __shfl_xor(vs, o);
    float rstd = rsqrtf(vs * (1.f / DMODEL) + 1e-5f);
    float rr[8];
#pragma unroll
    for (int i = 0; i < 8; i++) {
        int c = cb + i;
        rr[i] = (v[i] - m) * rstd * s[c] + b[c];
        if (MODE != 1) outf[(size_t)row * DMODEL + c] = rr[i];
        if (MODE != 0) outb[(size_t)row * DMODEL + c] = f2bf(rr[i]);
    }
    if (ROUTER) {
        float sc[NEXP];
#pragma unroll
        for (int e = 0; e < NEXP; e++) sc[e] = 0.f;
#pragma unroll
        for (int i = 0; i < 8; i++) {
            const float4* rp = (const float4*)(rdru + (size_t)(cb + i) * NEXP);
            float rv = rr[i];
#pragma unroll
            for (int e4 = 0; e4 < 8; e4++) {
                float4 q = rp[e4];
                sc[e4 * 4 + 0] += rv * q.x;
                sc[e4 * 4 + 1] += rv * q.y;
                sc[e4 * 4 + 2] += rv * q.z;
                sc[e4 * 4 + 3] += rv * q.w;
            }
        }
#pragma unroll
        for (int e = 0; e < NEXP; e++) {
#pragma unroll
            for (int o = 32; o; o >>= 1) sc[e] += __shfl_xor(sc[e], o);
        }
        if (lane == 0) {
            float* rp = rsc + (size_t)row * NEXP;
#pragma unroll
            for (int e = 0; e < NEXP; e++) rp[e] = sc[e];
        }
    }
}

// ---------------- device transpose tile: 64x64 fp32 [K][N] -> bf16 [N][K] ----------------
// LDS column XOR-swizzled by (row>>3)<<2: kills the 8-way read conflict.
__device__ __forceinline__ void wt_tile_body(char* ldsraw, const float* src,
                                             unsigned short* dst, int K, int N,
                                             int tx, int ty) {
    float (*tbuf)[68] = (float(*)[68])ldsraw;   // 64x68 floats = 17408B
    int tid = threadIdx.x;
    int k0 = ty * 64, n0 = tx * 64;
    int r = tid >> 2, cb4 = (tid & 3) * 4;
    int rk = ((r >> 3) & 7) << 2;               // per-row swizzle key
#pragma unroll
    for (int i = 0; i < 4; i++)
        *(float4*)&tbuf[r][(cb4 + i * 16) ^ rk] = *(const float4*)(src + (size_t)(k0 + r) * N + n0 + cb4 + i * 16);
    __syncthreads();
    int g = tid & 7, nr = tid >> 3;
    int gk = g << 2;                            // row (g*8+j) >> 3 == g
#pragma unroll
    for (int i = 0; i < 2; i++) {
        int n = nr + i * 32;
        bf16x8 v;
#pragma unroll
        for (int j = 0; j < 8; j++) v[j] = (short)f2bf(tbuf[g * 8 + j][n ^ gk]);
        *(bf16x8*)(dst + (size_t)(n0 + n) * K + k0 + g * 8) = v;
    }
}

// ---------------- device rdru fold tile ----------------
__device__ __forceinline__ void rdru_tile_body(char* ldsraw, const float* A,
                                               const float* W, float* C, int m0) {
    float (*Asf)[68] = (float(*)[68])ldsraw;
    float (*Wsf)[68] = (float(*)[68])(ldsraw + 4352);
    int tid = threadIdx.x;
    int ml = tid >> 2, kl = (tid & 3) << 2;
    const float* aptr = A + (size_t)(m0 + ml) * RRANK + kl;
    int kr = tid >> 4, nc = (tid & 15) << 2;
    bool wvalid = nc < NEXP;
    const float* wptr = W + (size_t)kr * NEXP + nc;
    int tm = (tid >> 4) << 2, tn = (tid & 15) << 2;
    float acc[4][4] = {{0.f}};
    for (int k0 = 0; k0 < RRANK; k0 += 16) {
        float4 av = *(const float4*)(aptr + k0);
        float4 wv = make_float4(0.f, 0.f, 0.f, 0.f);
        if (wvalid) wv = *(const float4*)(wptr + (size_t)k0 * NEXP);
        Asf[kl + 0][ml] = av.x; Asf[kl + 1][ml] = av.y;
        Asf[kl + 2][ml] = av.z; Asf[kl + 3][ml] = av.w;
        *(float4*)&Wsf[kr][nc] = wv;
        __syncthreads();
#pragma unroll
        for (int kk = 0; kk < 16; kk++) {
            float4 a4 = *(const float4*)&Asf[kk][tm];
            float4 w4 = *(const float4*)&Wsf[kk][tn];
            acc[0][0] += a4.x * w4.x; acc[0][1] += a4.x * w4.y; acc[0][2] += a4.x * w4.z; acc[0][3] += a4.x * w4.w;
            acc[1][0] += a4.y * w4.x; acc[1][1] += a4.y * w4.y; acc[1][2] += a4.y * w4.z; acc[1][3] += a4.y * w4.w;
            acc[2][0] += a4.z * w4.x; acc[2][1] += a4.z * w4.y; acc[2][2] += a4.z * w4.z; acc[2][3] += a4.z * w4.w;
            acc[3][0] += a4.w * w4.x; acc[3][1] += a4.w * w4.y; acc[3][2] += a4.w * w4.z; acc[3][3] += a4.w * w4.w;
        }
        __syncthreads();
    }
#pragma unroll
    for (int i = 0; i < 4; i++) {
        float* crow = C + (size_t)(m0 + tm + i) * NEXP;
#pragma unroll
        for (int j = 0; j < 4; j++) {
            int nn = tn + j;
            if (nn < NEXP) crow[nn] = acc[i][j];
        }
    }
}

// ---------------- layer-0 prep: wq/wk/wv transposes + biaspack/stats + rdru + LN1 ----------------
__global__ __launch_bounds__(256) void prep0_kernel(
    const float* __restrict__ wq, const float* __restrict__ wk, const float* __restrict__ wv,
    const float* __restrict__ bq, const float* __restrict__ bk, const float* __restrict__ bv,
    unsigned short* __restrict__ wqkvt, float* __restrict__ bqkv, int* __restrict__ stats,
    const float* __restrict__ rdw, const float* __restrict__ ruw, float* __restrict__ rdru,
    const float* __restrict__ xb, const float* __restrict__ ln1_s, const float* __restrict__ ln1_b,
    unsigned short* __restrict__ hb) {
    __shared__ char lds[17408];
    int bkid = blockIdx.x;
    int tid = threadIdx.x;
    if (bkid < 192) {
        int w = bkid >> 6, t = bkid & 63;
        const float* src = (w == 0) ? wq : (w == 1 ? wk : wv);
        wt_tile_body(lds, src, wqkvt + (size_t)w * DDU, 512, 512, t & 7, t >> 3);
    } else if (bkid < 198) {
        int i = (bkid - 192) * 256 + tid;
        float val = (i < 512) ? bq[i] : (i < 1024 ? bk[i - 512] : bv[i - 1024]);
        bqkv[i] = val;
        if (i < 160) stats[i] = 0;
    } else if (bkid < 206) {
        rdru_tile_body(lds, rdw, ruw, rdru, (bkid - 198) * 64);
    } else {
        ln_body(xb, ln1_s, ln1_b, hb, bkid - 206);
    }
}

// ---------------- shared GEMM body: 128x64 tile, BK=64 (proven loop, unchanged) ----------------
// VT: also scatter V-region cols (>=1024) of the QKV output into vT[b,h,d,s]
template <bool GELU, bool GATHER, bool EXPERT, bool OUTBF16, int SK, bool VT = false>
__device__ __forceinline__ void gemm_body(
    char* asb, char* bsb,
    unsigned int rb, unsigned int gx, unsigned int tot, int zidx,
    const unsigned short* Ab, const unsigned short* Wt,
    const float* bias, void* Cvoid, int M, int Nn, int Kk,
    const int* rowmap, const int* cntp, const int* offp, const int* tinfo,
    unsigned short* vtout = nullptr) {
    constexpr int RS  = 128;
    constexpr int CH  = 8;
    constexpr int RPI = 8;
    constexpr int AIW = 4;
    constexpr int BIW = 2;
    unsigned int lg = (rb & 7) * (tot >> 3) + (rb >> 3);
    unsigned int bx = lg % gx;
    unsigned int by = lg / gx;
    int n0 = bx * 64;
    int m0;
    size_t cbase = 0;
    int kbeg = 0, kend = Kk;
    if (EXPERT) {
        int t = by;
        if (t >= tinfo[0]) return;
        int e = tinfo[1 + 2 * t];
        m0 = tinfo[2 + 2 * t];
        M = cntp[e];
        Wt += (size_t)e * Nn * Kk;
        bias += (size_t)e * Nn;
        int oe = offp[e];
        cbase = (size_t)oe * Nn;
        if (GATHER) rowmap += oe;
        else Ab += (size_t)oe * Kk;
    } else {
        m0 = by * 128;
    }
    if (SK > 1) {
        int chunk = Kk / SK;
        kbeg = zidx * chunk;
        kend = kbeg + chunk;
        cbase = (size_t)zidx * M * Nn;
    }
    int tid = threadIdx.x;
    int wave = tid >> 6, lane = tid & 63;
    int wm = wave >> 1, wn = wave & 1;
    int l15 = lane & 15, l16 = lane >> 4;
    int c16 = lane & (CH - 1);
    int ro  = lane / CH;

    const char* aptr[AIW];
    const char* bptr[BIW];
#pragma unroll
    for (int j = 0; j < AIW; j++) {
        int rloc = j * RPI + ro;
        int row = wave * 32 + rloc;
        int grow = m0 + row;
        int arow = GATHER ? rowmap[grow] : grow;
        int srcoff = ((c16 ^ (rloc & (CH - 1))) << 4);
        aptr[j] = (const char*)Ab + (((size_t)arow * Kk) << 1) + srcoff;
    }
#pragma unroll
    for (int j = 0; j < BIW; j++) {
        int rloc = j * RPI + ro;
        int row = wave * 16 + rloc;
        int srcoff = ((c16 ^ (rloc & (CH - 1))) << 4);
        bptr[j] = (const char*)Wt + (((size_t)(n0 + row) * Kk) << 1) + srcoff;
    }

    f32x4 acc[4][2];
#pragma unroll
    for (int m = 0; m < 4; m++)
#pragma unroll
        for (int n = 0; n < 2; n++)
#pragma unroll
            for (int j = 0; j < 4; j++) acc[m][n][j] = 0.f;

    for (int k0 = kbeg; k0 < kend; k0 += 64) {
        size_t kb = (size_t)k0 << 1;
#pragma unroll
        for (int j = 0; j < AIW; j++) gl_lds16(aptr[j] + kb, asb + wave * 32 * RS + j * 1024);
#pragma unroll
        for (int j = 0; j < BIW; j++) gl_lds16(bptr[j] + kb, bsb + wave * 16 * RS + j * 1024);
        __syncthreads();
#pragma unroll
        for (int kk = 0; kk < 2; kk++) {
            int k8 = kk * 4 + l16;
            bf16x8 a[4], b[2];
#pragma unroll
            for (int m = 0; m < 4; m++) {
                int row = wm * 64 + m * 16 + l15;
                a[m] = *(const bf16x8*)(asb + row * RS + ((k8 * 16) ^ ((row & (CH - 1)) << 4)));
            }
#pragma unroll
            for (int n = 0; n < 2; n++) {
                int row = wn * 32 + n * 16 + l15;
                b[n] = *(const bf16x8*)(bsb + row * RS + ((k8 * 16) ^ ((row & (CH - 1)) << 4)));
            }
#pragma unroll
            for (int m = 0; m < 4; m++)
#pragma unroll
                for (int n = 0; n < 2; n++)
                    acc[m][n] = __builtin_amdgcn_mfma_f32_16x16x32_bf16(a[m], b[n], acc[m][n], 0, 0, 0);
        }
        __syncthreads();
    }

#pragma unroll
    for (int m = 0; m < 4; m++) {
#pragma unroll
        for (int n = 0; n < 2; n++) {
            int col = n0 + wn * 32 + n * 16 + l15;
            float bv = (SK == 1 && bias) ? bias[col] : 0.f;
#pragma unroll
            for (int j = 0; j < 4; j++) {
                int row = m0 + wm * 64 + m * 16 + l16 * 4 + j;
                if (row >= M) continue;
                float val = acc[m][n][j] + bv;
                if (SK == 1 && GELU) val = gelu_f(val);
                if (SK == 1 && OUTBF16) {
                    unsigned short obf = f2bf(val);
                    ((unsigned short*)Cvoid)[cbase + (size_t)row * Nn + col] = obf;
                    if (VT && col >= 1024) {
                        int cc = col - 1024;
                        int bb = row >> 10;
                        int s  = row & (SEQ - 1);
                        vtout[(size_t)(bb * 512 + cc) * SEQ + s] = obf;
                    }
                } else {
                    ((float*)Cvoid)[cbase + (size_t)row * Nn + col] = val;
                }
            }
        }
    }
}

// ---------------- QKV kernel: 768 GEMM blocks (+V scatter) + riders (RIDER 0: wot | 1: w2/ws2+stats) ----------------
template <int RIDER>
__global__ __launch_bounds__(256, 2) void qkv_kernel(
    const unsigned short* __restrict__ hb, const unsigned short* __restrict__ wqkvt,
    const float* __restrict__ bqkv, unsigned short* __restrict__ qkv_bf,
    unsigned short* __restrict__ vtout,
    const float* __restrict__ srcA, const float* __restrict__ srcB,
    unsigned short* __restrict__ dstA, unsigned short* __restrict__ dstB,
    int* __restrict__ stats) {
    __shared__ char lds[24576];
    unsigned int bid = blockIdx.x;
    if (bid < 768) {
        gemm_body<false, false, false, true, 1, true>(
            lds, lds + 16384, bid, 24, 768, 0,
            hb, wqkvt, bqkv, qkv_bf, NTOK, 1536, DMODEL, nullptr, nullptr, nullptr, nullptr,
            vtout);
    } else if (RIDER == 0) {
        int t = bid - 768;                    // 64 blocks: wo transpose
        wt_tile_body(lds, srcA, dstA, 512, 512, t & 7, t >> 3);
    } else {
        unsigned int eb = bid - 768;
        if (eb < 2048) {
            int e = eb >> 6, tt = eb & 63;
            wt_tile_body(lds, srcA + (size_t)e * DDU, dstA + (size_t)e * DDU,
                         512, 512, tt & 7, tt >> 3);
        } else if (eb < 2560) {
            int t = eb - 2048;
            wt_tile_body(lds, srcB, dstB, 4096, 512, t & 7, t >> 3);
        } else {
            if (threadIdx.x < 160) stats[threadIdx.x] = 0;
        }
    }
}

// ---------------- attention body (flat bid), pre-transposed Vt ----------------
__device__ __forceinline__ void attn_body(char* lds, unsigned int bid,
                                          const unsigned short* QKV,
                                          const unsigned short* Vt,
                                          unsigned short* O) {
    int qt = bid & 15, hh = (bid >> 4) & 7, bb = bid >> 7;
    char* Qs = lds;
    char* Ks = lds + 8192;
    char* Vs = lds + 16384;
    char* Ps = lds + 24576;
    int tid = threadIdx.x;
    int w = tid >> 6, l = tid & 63;
    int l15 = l & 15, l16 = l >> 4;

    {
        int r = tid >> 3, g = tid & 7;
        const unsigned short* qbase = QKV + (size_t)(bb * SEQ + qt * QBLK) * 1536 + hh * 64;
#pragma unroll
        for (int i = 0; i < 2; i++) {
            int row = r + i * 32;
            bf16x8 v = *(const bf16x8*)(qbase + (size_t)row * 1536 + g * 8);
            *(bf16x8*)(Qs + row * 128 + ((g * 16) ^ ((row & 7) << 4))) = v;
        }
    }
    f32x4 accO[4];
#pragma unroll
    for (int n = 0; n < 4; n++)
#pragma unroll
        for (int j = 0; j < 4; j++) accO[n][j] = 0.f;
    float m_r[4] = {-1e30f, -1e30f, -1e30f, -1e30f};
    float l_r[4] = {0.f, 0.f, 0.f, 0.f};

    const unsigned short* kbase = QKV + (size_t)(bb * SEQ) * 1536 + 512 + hh * 64;
    const unsigned short* vbase = Vt + (size_t)((bb * NHEAD + hh) * 64) * SEQ;

    for (int kt = 0; kt < SEQ / KBLK; kt++) {
        __syncthreads();
        {
            int r = tid >> 3, g = tid & 7;
#pragma unroll
            for (int i = 0; i < 2; i++) {
                int row = r + i * 32;
                bf16x8 kv = *(const bf16x8*)(kbase + (size_t)(kt * KBLK + row) * 1536 + g * 8);
                *(bf16x8*)(Ks + row * 128 + ((g * 16) ^ ((row & 7) << 4))) = kv;
                bf16x8 vv = *(const bf16x8*)(vbase + (size_t)row * SEQ + kt * KBLK + g * 8);
                *(bf16x8*)(Vs + row * 128 + ((g * 16) ^ ((row & 7) << 4))) = vv;
            }
        }
        __syncthreads();
        f32x4 s_acc[4];
#pragma unroll
        for (int n = 0; n < 4; n++)
#pragma unroll
            for (int j = 0; j < 4; j++) s_acc[n][j] = 0.f;
        __builtin_amdgcn_s_setprio(1);
#pragma unroll
        for (int st = 0; st < 2; st++) {
            int kb = st * 64 + l16 * 16;
            int qrow = w * 16 + l15;
            bf16x8 a = *(const bf16x8*)(Qs + qrow * 128 + (kb ^ ((qrow & 7) << 4)));
#pragma unroll
            for (int n = 0; n < 4; n++) {
                int kr = n * 16 + l15;
                bf16x8 b = *(const bf16x8*)(Ks + kr * 128 + (kb ^ ((kr & 7) << 4)));
                s_acc[n] = __builtin_amdgcn_mfma_f32_16x16x32_bf16(a, b, s_acc[n], 0, 0, 0);
            }
        }
        __builtin_amdgcn_s_setprio(0);
        char* pw = Ps + w * 2048;
#pragma unroll
        for (int j = 0; j < 4; j++) {
            float s0 = s_acc[0][j] * 0.125f, s1 = s_acc[1][j] * 0.125f;
            float s2 = s_acc[2][j] * 0.125f, s3 = s_acc[3][j] * 0.125f;
            float tmax = fmaxf(fmaxf(s0, s1), fmaxf(s2, s3));
#pragma unroll
            for (int o = 1; o < 16; o <<= 1) tmax = fmaxf(tmax, __shfl_xor(tmax, o));
            float mnew = fmaxf(m_r[j], tmax);
            float resc = __expf(m_r[j] - mnew);
            float p0 = __expf(s0 - mnew), p1 = __expf(s1 - mnew);
            float p2 = __expf(s2 - mnew), p3 = __expf(s3 - mnew);
            float ps = p0 + p1 + p2 + p3;
#pragma unroll
            for (int o = 1; o < 16; o <<= 1) ps += __shfl_xor(ps, o);
            l_r[j] = l_r[j] * resc + ps;
            m_r[j] = mnew;
            accO[0][j] *= resc; accO[1][j] *= resc;
            accO[2][j] *= resc; accO[3][j] *= resc;
            int prow = l16 * 4 + j;
            int sw = (prow & 7) << 4;
            *(unsigned short*)(pw + prow * 128 + ((2 * l15) ^ sw)) = f2bf(p0);
            *(unsigned short*)(pw + prow * 128 + ((2 * l15 + 32) ^ sw)) = f2bf(p1);
            *(unsigned short*)(pw + prow * 128 + ((2 * l15 + 64) ^ sw)) = f2bf(p2);
            *(unsigned short*)(pw + prow * 128 + ((2 * l15 + 96) ^ sw)) = f2bf(p3);
        }
        __builtin_amdgcn_s_setprio(1);
#pragma unroll
        for (int st = 0; st < 2; st++) {
            int kb = st * 64 + l16 * 16;
            bf16x8 pa = *(const bf16x8*)(pw + l15 * 128 + (kb ^ ((l15 & 7) << 4)));
#pragma unroll
            for (int n = 0; n < 4; n++) {
                int vr = n * 16 + l15;
                bf16x8 vb = *(const bf16x8*)(Vs + vr * 128 + (kb ^ ((vr & 7) << 4)));
                accO[n] = __builtin_amdgcn_mfma_f32_16x16x32_bf16(pa, vb, accO[n], 0, 0, 0);
            }
        }
        __builtin_amdgcn_s_setprio(0);
    }
    unsigned short* obase = O + (size_t)(bb * SEQ + qt * QBLK + w * 16) * DMODEL + hh * 64;
#pragma unroll
    for (int j = 0; j < 4; j++) {
        float inv = 1.f / l_r[j];
        int row = l16 * 4 + j;
#pragma unroll
        for (int n = 0; n < 4; n++)
            obase[(size_t)row * DMODEL + n * 16 + l15] = f2bf(accO[n][j] * inv);
    }
}

// ---------------- attention kernel + optional w1/ws1 riders (layer 0) ----------------
template <int RIDER>
__global__ __launch_bounds__(256, 2) void attn_kernel(
    const unsigned short* __restrict__ QKV, const unsigned short* __restrict__ Vt,
    unsigned short* __restrict__ O,
    const float* __restrict__ w1src, const float* __restrict__ ws1src,
    unsigned short* __restrict__ w1t, unsigned short* __restrict__ ws1t) {
    __shared__ char lds[32768];
    unsigned int bid = blockIdx.x;
    if (bid < 512) {
        attn_body(lds, bid, QKV, Vt, O);
    } else if (RIDER == 0) {
        unsigned int eb = bid - 512;
        if (eb < 2048) {
            int e = eb >> 6, tt = eb & 63;
            wt_tile_body(lds, w1src + (size_t)e * DDU, w1t + (size_t)e * DDU,
                         512, 512, tt & 7, tt >> 3);
        } else {
            int t = eb - 2048;
            wt_tile_body(lds, ws1src, ws1t, 512, 4096, t & 63, t >> 6);
        }
    }
}

// ---------------- O-proj kernel (flat, SK=2) + optional w2/ws2 riders (layer 0) ----------------
template <int RIDER>
__global__ __launch_bounds__(256, 2) void op_kernel(
    const unsigned short* __restrict__ t1b, const unsigned short* __restrict__ wot,
    float* __restrict__ pbuf,
    const float* __restrict__ w2src, const float* __restrict__ ws2src,
    unsigned short* __restrict__ w2t, unsigned short* __restrict__ ws2t) {
    __shared__ char lds[24576];
    unsigned int bid = blockIdx.x;
    if (bid < 512) {
        gemm_body<false, false, false, false, 2>(
            lds, lds + 16384, bid & 255, 8, 256, bid >> 8,
            t1b, wot, nullptr, pbuf, NTOK, DMODEL, DMODEL, nullptr, nullptr, nullptr, nullptr);
    } else if (RIDER == 0) {
        unsigned int eb = bid - 512;
        if (eb < 2048) {
            int e = eb >> 6, tt = eb & 63;
            wt_tile_body(lds, w2src + (size_t)e * DDU, w2t + (size_t)e * DDU,
                         512, 512, tt & 7, tt >> 3);
        } else {
            int t = eb - 2048;
            wt_tile_body(lds, ws2src, ws2t, 4096, 512, t & 7, t >> 3);
        }
    }
}

// ---------------- fused MLP stage 1 (+next-layer qkv/o transposes, biaspack, rdru) ----------------
__global__ __launch_bounds__(256, 2) void mlp1_kernel(
    const unsigned short* __restrict__ hb,
    const unsigned short* __restrict__ ws1t, const float* __restrict__ bs1,
    unsigned short* __restrict__ hidb,
    const unsigned short* __restrict__ w1t, const float* __restrict__ b1,
    unsigned short* __restrict__ ehid,
    const int* __restrict__ perm, const int* __restrict__ cnt,
    const int* __restrict__ poff, const int* __restrict__ tinfo,
    const float* __restrict__ nwq, const float* __restrict__ nwk,
    const float* __restrict__ nwv, const float* __restrict__ nwo,
    const float* __restrict__ nbq, const float* __restrict__ nbk, const float* __restrict__ nbv,
    unsigned short* __restrict__ wqkvt, unsigned short* __restrict__ wot,
    float* __restrict__ bqkv,
    const float* __restrict__ nrdw, const float* __restrict__ nruw, float* __restrict__ rdru) {
    __shared__ char lds[24576];
    unsigned int bid = blockIdx.x;
    if (bid < 2048) {
        gemm_body<true, false, false, true, 1>(
            lds, lds + 16384, bid, 64, 2048, 0,
            hb, ws1t, bs1, hidb, NTOK, HSHARED, DMODEL, nullptr, nullptr, nullptr, nullptr);
    } else if (bid < 3328) {
        gemm_body<true, true, true, true, 1>(
            lds, lds + 16384, bid - 2048, 8, 1280, 0,
            hb, w1t, b1, ehid, 0, HEXP, DMODEL, perm, cnt, poff, tinfo);
    } else {
        unsigned int eb = bid - 3328;
        if (eb < 256) {
            int w = eb >> 6, t = eb & 63;
            const float* src; unsigned short* dst;
            if (w == 0)      { src = nwq; dst = wqkvt; }
            else if (w == 1) { src = nwk; dst = wqkvt + DDU; }
            else if (w == 2) { src = nwv; dst = wqkvt + 2 * (size_t)DDU; }
            else             { src = nwo; dst = wot; }
            wt_tile_body(lds, src, dst, 512, 512, t & 7, t >> 3);
        } else if (eb < 262) {
            int i = (eb - 256) * 256 + threadIdx.x;
            float val = (i < 512) ? nbq[i] : (i < 1024 ? nbk[i - 512] : nbv[i - 1024]);
            bqkv[i] = val;
        } else {
            rdru_tile_body(lds, nrdw, nruw, rdru, (eb - 262) * 64);
        }
    }
}

// ---------------- fused MLP stage 2: shared FFN2 SK=1 || expert FFN2 (+next-layer w1/ws1 transposes) ----------------
__global__ __launch_bounds__(256, 2) void mlp2_kernel(
    const unsigned short* __restrict__ hidb,
    const unsigned short* __restrict__ ws2t, float* __restrict__ pbuf,
    const unsigned short* __restrict__ ehid,
    const unsigned short* __restrict__ w2t, const float* __restrict__ b2,
    unsigned short* __restrict__ eogb,
    const int* __restrict__ cnt, const int* __restrict__ poff,
    const int* __restrict__ tinfo,
    const float* __restrict__ nw1, const float* __restrict__ nws1,
    unsigned short* __restrict__ w1t, unsigned short* __restrict__ ws1t) {
    __shared__ char lds[24576];
    unsigned int bid = blockIdx.x;
    if (bid < 256) {
        gemm_body<false, false, false, false, 1>(
            lds, lds + 16384, bid, 8, 256, 0,
            hidb, ws2t, nullptr, pbuf, NTOK, DMODEL, HSHARED, nullptr, nullptr, nullptr, nullptr);
    } else if (bid < 1536) {
        gemm_body<false, false, true, true, 1>(
            lds, lds + 16384, bid - 256, 8, 1280, 0,
            ehid, w2t, b2, eogb, 0, DMODEL, HEXP, nullptr, cnt, poff, tinfo);
    } else {
        unsigned int eb = bid - 1536;
        if (eb < 2048) {
            int e = eb >> 6, tt = eb & 63;
            wt_tile_body(lds, nw1 + (size_t)e * DDU, w1t + (size_t)e * DDU,
                         512, 512, tt & 7, tt >> 3);
        } else {
            int t = eb - 2048;
            wt_tile_body(lds, nws1, ws1t, 512, 4096, t & 63, t >> 6);
        }
    }
}

// ---------------- router: shuffle-reduced stats + LAST-BLOCK scanaux fold ----------------
__global__ __launch_bounds__(256) void router_topk(const float* __restrict__ rsc,
                                                   float* __restrict__ topw,
                                                   int* __restrict__ topi,
                                                   int* __restrict__ cnt,
                                                   float* __restrict__ sumP,
                                                   float* __restrict__ zacc,
                                                   int* __restrict__ done,
                                                   int* __restrict__ poff,
                                                   int* __restrict__ tinfo,
                                                   int* __restrict__ perm,
                                                   float* __restrict__ out_aux, int l) {
    __shared__ float wP[4][NEXP];
    __shared__ int wC[4][NEXP];
    __shared__ float wZ[4];
    __shared__ int amLast;
    int tid = threadIdx.x;
    int wv = tid >> 6, lane = tid & 63;
    int n = blockIdx.x * 256 + tid;
    float sc[NEXP];
    float mx = -1e30f;
#pragma unroll
    for (int e = 0; e < NEXP; e++) { sc[e] = rsc[n * NEXP + e]; mx = fmaxf(mx, sc[e]); }
    float se = 0.f;
#pragma unroll
    for (int e = 0; e < NEXP; e++) { sc[e] = expf(sc[e] - mx); se += sc[e]; }
    float invse = 1.f / se;
    float lse = mx + logf(se);
    float z = lse * lse;
#pragma unroll
    for (int o = 32; o; o >>= 1) z += __shfl_xor(z, o);
    if (lane == 0) wZ[wv] = z;
#pragma unroll
    for (int e = 0; e < NEXP; e++) {
        float pv = sc[e] * invse;
#pragma unroll
        for (int o = 32; o; o >>= 1) pv += __shfl_xor(pv, o);
        if (lane == 0) wP[wv][e] = pv;
    }
    float tv[TOPK]; int ti[TOPK];
#pragma unroll
    for (int k = 0; k < TOPK; k++) {
        float best = -1.f; int bi = 0;
#pragma unroll
        for (int e = 0; e < NEXP; e++) {
            if (sc[e] > best) { best = sc[e]; bi = e; }
        }
        tv[k] = best * invse; ti[k] = bi; sc[bi] = -1.f;
    }
    float s4 = tv[0] + tv[1] + tv[2] + tv[3];
#pragma unroll
    for (int k = 0; k < TOPK; k++) {
        topw[n * TOPK + k] = tv[k] / s4;
        topi[n * TOPK + k] = ti[k];
    }
#pragma unroll
    for (int e = 0; e < NEXP; e++) {
        unsigned long long b0 = __ballot(ti[0] == e);
        unsigned long long b1 = __ballot(ti[1] == e);
        unsigned long long b2 = __ballot(ti[2] == e);
        unsigned long long b3 = __ballot(ti[3] == e);
        if (lane == 0)
            wC[wv][e] = __popcll(b0) + __popcll(b1) + __popcll(b2) + __popcll(b3);
    }
    __syncthreads();
    if (tid < NEXP) {
        atomicAdd(&sumP[tid], wP[0][tid] + wP[1][tid] + wP[2][tid] + wP[3][tid]);
        atomicAdd(&cnt[tid], wC[0][tid] + wC[1][tid] + wC[2][tid] + wC[3][tid]);
    }
    if (tid == 0) atomicAdd(zacc, wZ[0] + wZ[1] + wZ[2] + wZ[3]);
    // ---- last-block scanaux (no spinning: last arriver does the work) ----
    __syncthreads();
    __threadfence();
    if (tid == 0) amLast = (atomicAdd(done, 1) == (int)gridDim.x - 1);
    __syncthreads();
    if (amLast && tid < 64) {
        __threadfence();
        int laneid = tid;
        int c = (laneid < NEXP) ? atomicAdd(&cnt[laneid], 0) : 0;   // coherent read
        int nt = (c + 127) >> 7;
        int x = nt;
#pragma unroll
        for (int o = 1; o < 32; o <<= 1) {
            int y = __shfl_up(x, o);
            if (laneid >= o) x += y;
        }
        int excl = x - nt;
        if (laneid < NEXP) {
            poff[laneid] = excl * 128;
            for (int i = 0; i < nt; i++) {
                tinfo[1 + 2 * (excl + i)] = laneid;
                tinfo[2 + 2 * (excl + i)] = i * 128;
            }
            for (int i = c; i < nt * 128; i++) perm[excl * 128 + i] = 0;
        }
        float sp = (laneid < NEXP) ? atomicAdd(&sumP[laneid], 0.f) : 0.f;
        float lb = (laneid < NEXP) ? ((float)c / (float)NTOK) * (sp / (float)NTOK) : 0.f;
#pragma unroll
        for (int o = 32; o; o >>= 1) lb += __shfl_xor(lb, o);
        if (laneid == 31) {
            tinfo[0] = x;
            out_aux[l] = lb * (float)NEXP / (float)TOPK;
            out_aux[NLAYER + l] = atomicAdd(zacc, 0.f) / (float)NTOK;
        }
    }
}

// ---------------- scatter: LDS-aggregated per-block bases ----------------
__global__ __launch_bounds__(256) void scatter_kernel(const int* __restrict__ topi,
                                                      const int* __restrict__ poff,
                                                      int* __restrict__ cursor,
                                                      int* __restrict__ perm,
                                                      int* __restrict__ pos) {
    __shared__ int lcnt[NEXP];
    __shared__ int lbase[NEXP];
    if (threadIdx.x < NEXP) lcnt[threadIdx.x] = 0;
    __syncthreads();
    int i = blockIdx.x * 256 + threadIdx.x;
    int e = topi[i];
    int lr = atomicAdd(&lcnt[e], 1);
    __syncthreads();
    if (threadIdx.x < NEXP && lcnt[threadIdx.x] > 0)
        lbase[threadIdx.x] = atomicAdd(&cursor[threadIdx.x], lcnt[threadIdx.x]);
    __syncthreads();
    int g = poff[e] + lbase[e] + lr;
    perm[g] = i >> 2;
    pos[i] = g;
}

// ---------------- launcher ----------------
extern "C" void kernel_launch(void* const* d_in, const int* in_sizes, int n_in,
                              void* d_out, int out_size, void* d_ws, size_t ws_size,
                              hipStream_t stream) {
    (void)in_sizes; (void)n_in; (void)out_size; (void)ws_size;
    const float* x_in  = (const float*)d_in[0];
    const float* ln1_s = (const float*)d_in[1];
    const float* ln1_b = (const float*)d_in[2];
    const float* ln2_s = (const float*)d_in[3];
    const float* ln2_b = (const float*)d_in[4];
    const float* wq = (const float*)d_in[5];
    const float* bq = (const float*)d_in[6];
    const float* wk = (const float*)d_in[7];
    const float* bk = (const float*)d_in[8];
    const float* wv = (const float*)d_in[9];
    const float* bv = (const float*)d_in[10];
    const float* wo = (const float*)d_in[11];
    const float* bo = (const float*)d_in[12];
    const float* rdw = (const float*)d_in[13];
    const float* ruw = (const float*)d_in[14];
    const float* w1 = (const float*)d_in[15];
    const float* b1 = (const float*)d_in[16];
    const float* w2 = (const float*)d_in[17];
    const float* b2 = (const float*)d_in[18];
    const float* ws1 = (const float*)d_in[19];
    const float* bs1 = (const float*)d_in[20];
    const float* ws2 = (const float*)d_in[21];
    const float* bs2 = (const float*)d_in[22];
    const float* fn_s = (const float*)d_in[23];
    const float* fn_b = (const float*)d_in[24];

    float* ws = (float*)d_ws;
    const size_t ND = (size_t)NTOK * DMODEL;
    const size_t PADROWS = (size_t)MAXTILE * 128;
    size_t o = 0;
    float* xb  = ws + o; o += ND;
    unsigned short* hb     = (unsigned short*)(ws + o); o += ND / 2;
    unsigned short* qkv_bf = (unsigned short*)(ws + o); o += (size_t)NTOK * 1536 / 2;
    unsigned short* vT     = (unsigned short*)(ws + o); o += ND / 2;
    unsigned short* t1b    = (unsigned short*)(ws + o); o += ND / 2;
    unsigned short* hidb   = (unsigned short*)(ws + o); o += (size_t)NTOK * HSHARED / 2;
    unsigned short* ehid   = (unsigned short*)(ws + o); o += PADROWS * HEXP / 2;
    unsigned short* eogb   = (unsigned short*)(ws + o); o += PADROWS * DMODEL / 2;
    float* pbuf = ws + o; o += 4 * ND;                 // split-K partials (max SK=4)
    float* rdru = ws + o; o += (size_t)DMODEL * NEXP;
    float* rsc  = ws + o; o += (size_t)NTOK * NEXP;
    float* topw = ws + o; o += (size_t)NTOK * TOPK;
    float* bqkv = ws + o; o += 1536;
    int* topi = (int*)(ws + o); o += (size_t)NTOK * TOPK;
    int* pos  = (int*)(ws + o); o += (size_t)NTOK * TOPK;
    int* perm = (int*)(ws + o); o += PADROWS;
    int* stats = (int*)(ws + o); o += 256;
    int* tinfo = (int*)(ws + o); o += 512;
    int* cnt = stats;
    int* cursor = stats + 32;
    int* poff = stats + 64;
    float* sumP = (float*)(stats + 96);
    float* zacc = sumP + 32;
    int* done = stats + 129;         // zeroed with stats[0..160)
    unsigned short* wbf = (unsigned short*)(ws + o);
    unsigned short* wqkvt = wbf;
    unsigned short* wot  = wqkvt + 3 * (size_t)DDU;
    unsigned short* w1t  = wot + DDU;
    unsigned short* w2t  = w1t + (size_t)NEXP * DDU;
    unsigned short* ws1t = w2t + (size_t)NEXP * DDU;
    unsigned short* ws2t = ws1t + (size_t)DMODEL * HSHARED;

    float* out_x = (float*)d_out;
    float* out_aux = out_x + ND;

    hipMemcpyAsync(xb, x_in, ND * sizeof(float), hipMemcpyDeviceToDevice, stream);

    dim3 blk(256);

    for (int l = 0; l < NLAYER; l++) {
        const size_t DD = (size_t)DMODEL * DMODEL;
        bool hasNext = (l + 1 < NLAYER);
        int lnx = hasNext ? (l + 1) : l;
        if (l == 0) {
            prep0_kernel<<<1230, blk, 0, stream>>>(
                wq, wk, wv, bq, bk, bv, wqkvt, bqkv, stats,
                rdw, ruw, rdru, xb, ln1_s, ln1_b, hb);
            qkv_kernel<0><<<832, blk, 0, stream>>>(
                hb, wqkvt, bqkv, qkv_bf, vT, wo, nullptr, wot, nullptr, nullptr);
        } else {
            qkv_kernel<1><<<3329, blk, 0, stream>>>(
                hb, wqkvt, bqkv, qkv_bf, vT,
                w2 + (size_t)l * NEXP * DD, ws2 + (size_t)l * HSHARED * DMODEL,
                w2t, ws2t, stats);
        }
        // ---- attention (V pre-transposed by qkv epilogue; +layer-0: w1/ws1 transposes) ----
        if (l == 0)
            attn_kernel<0><<<3072, blk, 0, stream>>>(qkv_bf, vT, t1b, w1, ws1, w1t, ws1t);
        else
            attn_kernel<1><<<512, blk, 0, stream>>>(qkv_bf, vT, t1b, nullptr, nullptr, nullptr, nullptr);
        // ---- out proj SK=2 (+layer-0: w2/ws2 transposes) ----
        if (l == 0)
            op_kernel<0><<<3072, blk, 0, stream>>>(t1b, wot, pbuf, w2, ws2, w2t, ws2t);
        else
            op_kernel<1><<<512, blk, 0, stream>>>(t1b, wot, pbuf, nullptr, nullptr, nullptr, nullptr);
        // ---- fused reduce+LN2+router-scores ----
        reduceln_kernel<2, false, 1, true><<<NTOK / 4, blk, 0, stream>>>(
            pbuf, bo + l * DMODEL, nullptr, nullptr, nullptr, xb,
            ln2_s + l * DMODEL, ln2_b + l * DMODEL, nullptr, hb, rdru, rsc);
        // ---- router top-k + stats + last-block scanaux ----
        router_topk<<<NTOK / 256, blk, 0, stream>>>(
            rsc, topw, topi, cnt, sumP, zacc, done, poff, tinfo, perm, out_aux, l);
        scatter_kernel<<<NTOK * TOPK / 256, blk, 0, stream>>>(topi, poff, cursor, perm, pos);
        // ---- fused MLP stage 1 (+next-layer qkv/o transposes + biaspack + rdru) ----
        int ln1g = hasNext ? 3598 : 3328;
        mlp1_kernel<<<ln1g, blk, 0, stream>>>(
            hb, ws1t, bs1 + (size_t)l * HSHARED, hidb,
            w1t, b1 + (size_t)l * NEXP * HEXP, ehid,
            perm, cnt, poff, tinfo,
            wq + (size_t)lnx * DD, wk + (size_t)lnx * DD,
            wv + (size_t)lnx * DD, wo + (size_t)lnx * DD,
            bq + (size_t)lnx * DMODEL, bk + (size_t)lnx * DMODEL, bv + (size_t)lnx * DMODEL,
            wqkvt, wot, bqkv,
            rdw + (size_t)lnx * DMODEL * RRANK, ruw + (size_t)lnx * RRANK * NEXP, rdru);
        // ---- fused MLP stage 2: shared FFN2 SK=1 || expert FFN2 (+next-layer w1/ws1 transposes) ----
        int ln2g = hasNext ? 4096 : 1536;
        mlp2_kernel<<<ln2g, blk, 0, stream>>>(
            hidb, ws2t, pbuf,
            ehid, w2t, b2 + (size_t)l * NEXP * DMODEL, eogb,
            cnt, poff, tinfo,
            w1 + (size_t)lnx * NEXP * DD, ws1 + (size_t)lnx * DMODEL * HSHARED,
            w1t, ws1t);
        // ---- fused reduce+MoE-combine+LN (next layer or final) ----
        if (hasNext) {
            reduceln_kernel<1, true, 1, false><<<NTOK / 4, blk, 0, stream>>>(
                pbuf, bs2 + l * DMODEL, eogb, topw, pos, xb,
                ln1_s + (l + 1) * DMODEL, ln1_b + (l + 1) * DMODEL, nullptr, hb, nullptr, nullptr);
        } else {
            reduceln_kernel<1, true, 0, false><<<NTOK / 4, blk, 0, stream>>>(
                pbuf, bs2 + l * DMODEL, eogb, topw, pos, xb,
                fn_s, fn_b, out_x, nullptr, nullptr, nullptr);
        }
    }
}

// Round 27
// 479.568 us; speedup vs baseline: 1.0368x; 1.0368x over previous
//
#include <hip/hip_runtime.h>
#include <math.h>

// ---- problem constants ----
#define NTOK    4096      // B*S
#define DMODEL  512
#define NEXP    32
#define RRANK   64
#define HEXP    512
#define HSHARED 4096
#define SEQ     1024
#define BATCH   4
#define NHEAD   8
#define TOPK    4
#define NLAYER  2
#define QBLK    64
#define KBLK    64
#define MAXTILE 160       // max padded expert m-tiles: 16384/128 + 32
#define DDU     262144    // 512*512

typedef __attribute__((ext_vector_type(8))) short bf16x8;
typedef __attribute__((ext_vector_type(4))) float f32x4;

// gelu_tanh(x) == x * sigmoid(2*0.7978845608*(x + 0.044715 x^3)); one v_exp + rcp
__device__ __forceinline__ float gelu_f(float x) {
    float u = 1.5957691216057308f * (x + 0.044715f * x * x * x);
    return x * __builtin_amdgcn_rcpf(1.f + __expf(-u));
}
__device__ __forceinline__ unsigned short f2bf(float f) {
    unsigned int u = __float_as_uint(f);
    u += 0x7FFFu + ((u >> 16) & 1u);
    return (unsigned short)(u >> 16);
}
__device__ __forceinline__ float bf2f(unsigned short u) {
    return __uint_as_float((unsigned int)u << 16);
}
// async global->LDS, 16B per lane; LDS dest wave-uniform base + lane*16
__device__ __forceinline__ void gl_lds16(const void* g, void* l) {
    __builtin_amdgcn_global_load_lds(
        (const __attribute__((address_space(1))) void*)g,
        (__attribute__((address_space(3))) void*)l, 16, 0, 0);
}

// ---------------- LayerNorm body (bf16 out), rowblk covers 4 rows ----------------
__device__ __forceinline__ void ln_body(const float* x, const float* s, const float* b,
                                        unsigned short* outb, int rowblk) {
    int wave = threadIdx.x >> 6, lane = threadIdx.x & 63;
    int row = rowblk * 4 + wave;
    const float* xr = x + (size_t)row * DMODEL;
    float v[8];
    float sum = 0.f;
#pragma unroll
    for (int i = 0; i < 8; i++) { v[i] = xr[lane + i * 64]; sum += v[i]; }
#pragma unroll
    for (int o = 32; o; o >>= 1) sum += __shfl_xor(sum, o);
    float m = sum * (1.f / DMODEL);
    float vs = 0.f;
#pragma unroll
    for (int i = 0; i < 8; i++) { float d = v[i] - m; vs += d * d; }
#pragma unroll
    for (int o = 32; o; o >>= 1) vs += __shfl_xor(vs, o);
    float rstd = rsqrtf(vs * (1.f / DMODEL) + 1e-5f);
#pragma unroll
    for (int i = 0; i < 8; i++) {
        int c = lane + i * 64;
        outb[(size_t)row * DMODEL + c] = f2bf((v[i] - m) * rstd * s[c] + b[c]);
    }
}

// ---------------- fused split-K reduce (+bias +residual +MoE) + LayerNorm (+router scores) ----------------
template <int SK, bool MOE, int MODE, bool ROUTER = false>
__global__ __launch_bounds__(256) void reduceln_kernel(
    const float* __restrict__ pbuf, const float* __restrict__ bias,
    const unsigned short* __restrict__ eogb, const float* __restrict__ topw,
    const int* __restrict__ pos, float* __restrict__ xb,
    const float* __restrict__ s, const float* __restrict__ b,
    float* __restrict__ outf, unsigned short* __restrict__ outb,
    const float* __restrict__ rdru, float* __restrict__ rsc) {
    int wave = threadIdx.x >> 6, lane = threadIdx.x & 63;
    int row = blockIdx.x * 4 + wave;
    int cb = lane * 8;
    size_t base = (size_t)row * DMODEL + cb;
    float v[8];
    {
        float4 a0 = *(const float4*)(xb + base);
        float4 a1 = *(const float4*)(xb + base + 4);
        float4 b0 = *(const float4*)(bias + cb);
        float4 b1 = *(const float4*)(bias + cb + 4);
        v[0] = a0.x + b0.x; v[1] = a0.y + b0.y; v[2] = a0.z + b0.z; v[3] = a0.w + b0.w;
        v[4] = a1.x + b1.x; v[5] = a1.y + b1.y; v[6] = a1.z + b1.z; v[7] = a1.w + b1.w;
    }
#pragma unroll
    for (int sk = 0; sk < SK; sk++) {
        const float* p = pbuf + (size_t)sk * NTOK * DMODEL + base;
        float4 p0 = *(const float4*)p;
        float4 p1 = *(const float4*)(p + 4);
        v[0] += p0.x; v[1] += p0.y; v[2] += p0.z; v[3] += p0.w;
        v[4] += p1.x; v[5] += p1.y; v[6] += p1.z; v[7] += p1.w;
    }
    if (MOE) {
#pragma unroll
        for (int k = 0; k < TOPK; k++) {
            float w = topw[row * TOPK + k];
            bf16x8 e = *(const bf16x8*)(eogb + (size_t)pos[row * TOPK + k] * DMODEL + cb);
#pragma unroll
            for (int i = 0; i < 8; i++) v[i] += w * bf2f((unsigned short)e[i]);
        }
    }
    *(float4*)(xb + base) = make_float4(v[0], v[1], v[2], v[3]);
    *(float4*)(xb + base + 4) = make_float4(v[4], v[5], v[6], v[7]);
    float sum = 0.f;
#pragma unroll
    for (int i = 0; i < 8; i++) sum += v[i];
#pragma unroll
    for (int o = 32; o; o >>= 1) sum += __shfl_xor(sum, o);
    float m = sum * (1.f / DMODEL);
    float vs = 0.f;
#pragma unroll
    for (int i = 0; i < 8; i++) { float d = v[i] - m; vs += d * d; }
#pragma unroll
    for (int o = 32; o; o >>= 1) vs += __shfl_xor(vs, o);
    float rstd = rsqrtf(vs * (1.f / DMODEL) + 1e-5f);
    float rr[8];
#pragma unroll
    for (int i = 0; i < 8; i++) {
        int c = cb + i;
        rr[i] = (v[i] - m) * rstd * s[c] + b[c];
        if (MODE != 1) outf[(size_t)row * DMODEL + c] = rr[i];
        if (MODE != 0) outb[(size_t)row * DMODEL + c] = f2bf(rr[i]);
    }
    if (ROUTER) {
        float sc[NEXP];
#pragma unroll
        for (int e = 0; e < NEXP; e++) sc[e] = 0.f;
#pragma unroll
        for (int i = 0; i < 8; i++) {
            const float4* rp = (const float4*)(rdru + (size_t)(cb + i) * NEXP);
            float rv = rr[i];
#pragma unroll
            for (int e4 = 0; e4 < 8; e4++) {
                float4 q = rp[e4];
                sc[e4 * 4 + 0] += rv * q.x;
                sc[e4 * 4 + 1] += rv * q.y;
                sc[e4 * 4 + 2] += rv * q.z;
                sc[e4 * 4 + 3] += rv * q.w;
            }
        }
#pragma unroll
        for (int e = 0; e < NEXP; e++) {
#pragma unroll
            for (int o = 32; o; o >>= 1) sc[e] += __shfl_xor(sc[e], o);
        }
        if (lane == 0) {
            float* rp = rsc + (size_t)row * NEXP;
#pragma unroll
            for (int e = 0; e < NEXP; e++) rp[e] = sc[e];
        }
    }
}

// ---------------- device transpose tile: 64x64 fp32 [K][N] -> bf16 [N][K] ----------------
// LDS column XOR-swizzled by (row>>3)<<2: kills the 8-way read conflict.
__device__ __forceinline__ void wt_tile_body(char* ldsraw, const float* src,
                                             unsigned short* dst, int K, int N,
                                             int tx, int ty) {
    float (*tbuf)[68] = (float(*)[68])ldsraw;   // 64x68 floats = 17408B
    int tid = threadIdx.x;
    int k0 = ty * 64, n0 = tx * 64;
    int r = tid >> 2, cb4 = (tid & 3) * 4;
    int rk = ((r >> 3) & 7) << 2;               // per-row swizzle key
#pragma unroll
    for (int i = 0; i < 4; i++)
        *(float4*)&tbuf[r][(cb4 + i * 16) ^ rk] = *(const float4*)(src + (size_t)(k0 + r) * N + n0 + cb4 + i * 16);
    __syncthreads();
    int g = tid & 7, nr = tid >> 3;
    int gk = g << 2;                            // row (g*8+j) >> 3 == g
#pragma unroll
    for (int i = 0; i < 2; i++) {
        int n = nr + i * 32;
        bf16x8 v;
#pragma unroll
        for (int j = 0; j < 8; j++) v[j] = (short)f2bf(tbuf[g * 8 + j][n ^ gk]);
        *(bf16x8*)(dst + (size_t)(n0 + n) * K + k0 + g * 8) = v;
    }
}

// ---------------- device rdru fold tile ----------------
__device__ __forceinline__ void rdru_tile_body(char* ldsraw, const float* A,
                                               const float* W, float* C, int m0) {
    float (*Asf)[68] = (float(*)[68])ldsraw;
    float (*Wsf)[68] = (float(*)[68])(ldsraw + 4352);
    int tid = threadIdx.x;
    int ml = tid >> 2, kl = (tid & 3) << 2;
    const float* aptr = A + (size_t)(m0 + ml) * RRANK + kl;
    int kr = tid >> 4, nc = (tid & 15) << 2;
    bool wvalid = nc < NEXP;
    const float* wptr = W + (size_t)kr * NEXP + nc;
    int tm = (tid >> 4) << 2, tn = (tid & 15) << 2;
    float acc[4][4] = {{0.f}};
    for (int k0 = 0; k0 < RRANK; k0 += 16) {
        float4 av = *(const float4*)(aptr + k0);
        float4 wv = make_float4(0.f, 0.f, 0.f, 0.f);
        if (wvalid) wv = *(const float4*)(wptr + (size_t)k0 * NEXP);
        Asf[kl + 0][ml] = av.x; Asf[kl + 1][ml] = av.y;
        Asf[kl + 2][ml] = av.z; Asf[kl + 3][ml] = av.w;
        *(float4*)&Wsf[kr][nc] = wv;
        __syncthreads();
#pragma unroll
        for (int kk = 0; kk < 16; kk++) {
            float4 a4 = *(const float4*)&Asf[kk][tm];
            float4 w4 = *(const float4*)&Wsf[kk][tn];
            acc[0][0] += a4.x * w4.x; acc[0][1] += a4.x * w4.y; acc[0][2] += a4.x * w4.z; acc[0][3] += a4.x * w4.w;
            acc[1][0] += a4.y * w4.x; acc[1][1] += a4.y * w4.y; acc[1][2] += a4.y * w4.z; acc[1][3] += a4.y * w4.w;
            acc[2][0] += a4.z * w4.x; acc[2][1] += a4.z * w4.y; acc[2][2] += a4.z * w4.z; acc[2][3] += a4.z * w4.w;
            acc[3][0] += a4.w * w4.x; acc[3][1] += a4.w * w4.y; acc[3][2] += a4.w * w4.z; acc[3][3] += a4.w * w4.w;
        }
        __syncthreads();
    }
#pragma unroll
    for (int i = 0; i < 4; i++) {
        float* crow = C + (size_t)(m0 + tm + i) * NEXP;
#pragma unroll
        for (int j = 0; j < 4; j++) {
            int nn = tn + j;
            if (nn < NEXP) crow[nn] = acc[i][j];
        }
    }
}

// ---------------- layer-0 prep: wq/wk/wv transposes + biaspack/stats + rdru + LN1 ----------------
__global__ __launch_bounds__(256) void prep0_kernel(
    const float* __restrict__ wq, const float* __restrict__ wk, const float* __restrict__ wv,
    const float* __restrict__ bq, const float* __restrict__ bk, const float* __restrict__ bv,
    unsigned short* __restrict__ wqkvt, float* __restrict__ bqkv, int* __restrict__ stats,
    const float* __restrict__ rdw, const float* __restrict__ ruw, float* __restrict__ rdru,
    const float* __restrict__ xb, const float* __restrict__ ln1_s, const float* __restrict__ ln1_b,
    unsigned short* __restrict__ hb) {
    __shared__ char lds[17408];
    int bkid = blockIdx.x;
    int tid = threadIdx.x;
    if (bkid < 192) {
        int w = bkid >> 6, t = bkid & 63;
        const float* src = (w == 0) ? wq : (w == 1 ? wk : wv);
        wt_tile_body(lds, src, wqkvt + (size_t)w * DDU, 512, 512, t & 7, t >> 3);
    } else if (bkid < 198) {
        int i = (bkid - 192) * 256 + tid;
        float val = (i < 512) ? bq[i] : (i < 1024 ? bk[i - 512] : bv[i - 1024]);
        bqkv[i] = val;
        if (i < 160) stats[i] = 0;
    } else if (bkid < 206) {
        rdru_tile_body(lds, rdw, ruw, rdru, (bkid - 198) * 64);
    } else {
        ln_body(xb, ln1_s, ln1_b, hb, bkid - 206);
    }
}

// ---------------- shared GEMM body: 128x64 tile, BK=64 (proven loop, unchanged) ----------------
// VT: also scatter V-region cols (>=1024) of the QKV output into vT[b,h,d,s]
template <bool GELU, bool GATHER, bool EXPERT, bool OUTBF16, int SK, bool VT = false>
__device__ __forceinline__ void gemm_body(
    char* asb, char* bsb,
    unsigned int rb, unsigned int gx, unsigned int tot, int zidx,
    const unsigned short* Ab, const unsigned short* Wt,
    const float* bias, void* Cvoid, int M, int Nn, int Kk,
    const int* rowmap, const int* cntp, const int* offp, const int* tinfo,
    unsigned short* vtout = nullptr) {
    constexpr int RS  = 128;
    constexpr int CH  = 8;
    constexpr int RPI = 8;
    constexpr int AIW = 4;
    constexpr int BIW = 2;
    unsigned int lg = (rb & 7) * (tot >> 3) + (rb >> 3);
    unsigned int bx = lg % gx;
    unsigned int by = lg / gx;
    int n0 = bx * 64;
    int m0;
    size_t cbase = 0;
    int kbeg = 0, kend = Kk;
    if (EXPERT) {
        int t = by;
        if (t >= tinfo[0]) return;
        int e = tinfo[1 + 2 * t];
        m0 = tinfo[2 + 2 * t];
        M = cntp[e];
        Wt += (size_t)e * Nn * Kk;
        bias += (size_t)e * Nn;
        int oe = offp[e];
        cbase = (size_t)oe * Nn;
        if (GATHER) rowmap += oe;
        else Ab += (size_t)oe * Kk;
    } else {
        m0 = by * 128;
    }
    if (SK > 1) {
        int chunk = Kk / SK;
        kbeg = zidx * chunk;
        kend = kbeg + chunk;
        cbase = (size_t)zidx * M * Nn;
    }
    int tid = threadIdx.x;
    int wave = tid >> 6, lane = tid & 63;
    int wm = wave >> 1, wn = wave & 1;
    int l15 = lane & 15, l16 = lane >> 4;
    int c16 = lane & (CH - 1);
    int ro  = lane / CH;

    const char* aptr[AIW];
    const char* bptr[BIW];
#pragma unroll
    for (int j = 0; j < AIW; j++) {
        int rloc = j * RPI + ro;
        int row = wave * 32 + rloc;
        int grow = m0 + row;
        int arow = GATHER ? rowmap[grow] : grow;
        int srcoff = ((c16 ^ (rloc & (CH - 1))) << 4);
        aptr[j] = (const char*)Ab + (((size_t)arow * Kk) << 1) + srcoff;
    }
#pragma unroll
    for (int j = 0; j < BIW; j++) {
        int rloc = j * RPI + ro;
        int row = wave * 16 + rloc;
        int srcoff = ((c16 ^ (rloc & (CH - 1))) << 4);
        bptr[j] = (const char*)Wt + (((size_t)(n0 + row) * Kk) << 1) + srcoff;
    }

    f32x4 acc[4][2];
#pragma unroll
    for (int m = 0; m < 4; m++)
#pragma unroll
        for (int n = 0; n < 2; n++)
#pragma unroll
            for (int j = 0; j < 4; j++) acc[m][n][j] = 0.f;

    for (int k0 = kbeg; k0 < kend; k0 += 64) {
        size_t kb = (size_t)k0 << 1;
#pragma unroll
        for (int j = 0; j < AIW; j++) gl_lds16(aptr[j] + kb, asb + wave * 32 * RS + j * 1024);
#pragma unroll
        for (int j = 0; j < BIW; j++) gl_lds16(bptr[j] + kb, bsb + wave * 16 * RS + j * 1024);
        __syncthreads();
#pragma unroll
        for (int kk = 0; kk < 2; kk++) {
            int k8 = kk * 4 + l16;
            bf16x8 a[4], b[2];
#pragma unroll
            for (int m = 0; m < 4; m++) {
                int row = wm * 64 + m * 16 + l15;
                a[m] = *(const bf16x8*)(asb + row * RS + ((k8 * 16) ^ ((row & (CH - 1)) << 4)));
            }
#pragma unroll
            for (int n = 0; n < 2; n++) {
                int row = wn * 32 + n * 16 + l15;
                b[n] = *(const bf16x8*)(bsb + row * RS + ((k8 * 16) ^ ((row & (CH - 1)) << 4)));
            }
#pragma unroll
            for (int m = 0; m < 4; m++)
#pragma unroll
                for (int n = 0; n < 2; n++)
                    acc[m][n] = __builtin_amdgcn_mfma_f32_16x16x32_bf16(a[m], b[n], acc[m][n], 0, 0, 0);
        }
        __syncthreads();
    }

#pragma unroll
    for (int m = 0; m < 4; m++) {
#pragma unroll
        for (int n = 0; n < 2; n++) {
            int col = n0 + wn * 32 + n * 16 + l15;
            float bv = (SK == 1 && bias) ? bias[col] : 0.f;
#pragma unroll
            for (int j = 0; j < 4; j++) {
                int row = m0 + wm * 64 + m * 16 + l16 * 4 + j;
                if (row >= M) continue;
                float val = acc[m][n][j] + bv;
                if (SK == 1 && GELU) val = gelu_f(val);
                if (SK == 1 && OUTBF16) {
                    unsigned short obf = f2bf(val);
                    ((unsigned short*)Cvoid)[cbase + (size_t)row * Nn + col] = obf;
                    if (VT && col >= 1024) {
                        int cc = col - 1024;
                        int bb = row >> 10;
                        int s  = row & (SEQ - 1);
                        vtout[(size_t)(bb * 512 + cc) * SEQ + s] = obf;
                    }
                } else {
                    ((float*)Cvoid)[cbase + (size_t)row * Nn + col] = val;
                }
            }
        }
    }
}

// ---------------- QKV kernel: 768 GEMM blocks (+V scatter) + riders (RIDER 0: wot | 1: w2/ws2+stats) ----------------
template <int RIDER>
__global__ __launch_bounds__(256, 2) void qkv_kernel(
    const unsigned short* __restrict__ hb, const unsigned short* __restrict__ wqkvt,
    const float* __restrict__ bqkv, unsigned short* __restrict__ qkv_bf,
    unsigned short* __restrict__ vtout,
    const float* __restrict__ srcA, const float* __restrict__ srcB,
    unsigned short* __restrict__ dstA, unsigned short* __restrict__ dstB,
    int* __restrict__ stats) {
    __shared__ char lds[24576];
    unsigned int bid = blockIdx.x;
    if (bid < 768) {
        gemm_body<false, false, false, true, 1, true>(
            lds, lds + 16384, bid, 24, 768, 0,
            hb, wqkvt, bqkv, qkv_bf, NTOK, 1536, DMODEL, nullptr, nullptr, nullptr, nullptr,
            vtout);
    } else if (RIDER == 0) {
        int t = bid - 768;                    // 64 blocks: wo transpose
        wt_tile_body(lds, srcA, dstA, 512, 512, t & 7, t >> 3);
    } else {
        unsigned int eb = bid - 768;
        if (eb < 2048) {
            int e = eb >> 6, tt = eb & 63;
            wt_tile_body(lds, srcA + (size_t)e * DDU, dstA + (size_t)e * DDU,
                         512, 512, tt & 7, tt >> 3);
        } else if (eb < 2560) {
            int t = eb - 2048;
            wt_tile_body(lds, srcB, dstB, 4096, 512, t & 7, t >> 3);
        } else {
            if (threadIdx.x < 160) stats[threadIdx.x] = 0;
        }
    }
}

// ---------------- attention body (flat bid), pre-transposed Vt ----------------
__device__ __forceinline__ void attn_body(char* lds, unsigned int bid,
                                          const unsigned short* QKV,
                                          const unsigned short* Vt,
                                          unsigned short* O) {
    int qt = bid & 15, hh = (bid >> 4) & 7, bb = bid >> 7;
    char* Qs = lds;
    char* Ks = lds + 8192;
    char* Vs = lds + 16384;
    char* Ps = lds + 24576;
    int tid = threadIdx.x;
    int w = tid >> 6, l = tid & 63;
    int l15 = l & 15, l16 = l >> 4;

    {
        int r = tid >> 3, g = tid & 7;
        const unsigned short* qbase = QKV + (size_t)(bb * SEQ + qt * QBLK) * 1536 + hh * 64;
#pragma unroll
        for (int i = 0; i < 2; i++) {
            int row = r + i * 32;
            bf16x8 v = *(const bf16x8*)(qbase + (size_t)row * 1536 + g * 8);
            *(bf16x8*)(Qs + row * 128 + ((g * 16) ^ ((row & 7) << 4))) = v;
        }
    }
    f32x4 accO[4];
#pragma unroll
    for (int n = 0; n < 4; n++)
#pragma unroll
        for (int j = 0; j < 4; j++) accO[n][j] = 0.f;
    float m_r[4] = {-1e30f, -1e30f, -1e30f, -1e30f};
    float l_r[4] = {0.f, 0.f, 0.f, 0.f};

    const unsigned short* kbase = QKV + (size_t)(bb * SEQ) * 1536 + 512 + hh * 64;
    const unsigned short* vbase = Vt + (size_t)((bb * NHEAD + hh) * 64) * SEQ;

    for (int kt = 0; kt < SEQ / KBLK; kt++) {
        __syncthreads();
        {
            int r = tid >> 3, g = tid & 7;
#pragma unroll
            for (int i = 0; i < 2; i++) {
                int row = r + i * 32;
                bf16x8 kv = *(const bf16x8*)(kbase + (size_t)(kt * KBLK + row) * 1536 + g * 8);
                *(bf16x8*)(Ks + row * 128 + ((g * 16) ^ ((row & 7) << 4))) = kv;
                bf16x8 vv = *(const bf16x8*)(vbase + (size_t)row * SEQ + kt * KBLK + g * 8);
                *(bf16x8*)(Vs + row * 128 + ((g * 16) ^ ((row & 7) << 4))) = vv;
            }
        }
        __syncthreads();
        f32x4 s_acc[4];
#pragma unroll
        for (int n = 0; n < 4; n++)
#pragma unroll
            for (int j = 0; j < 4; j++) s_acc[n][j] = 0.f;
        __builtin_amdgcn_s_setprio(1);
#pragma unroll
        for (int st = 0; st < 2; st++) {
            int kb = st * 64 + l16 * 16;
            int qrow = w * 16 + l15;
            bf16x8 a = *(const bf16x8*)(Qs + qrow * 128 + (kb ^ ((qrow & 7) << 4)));
#pragma unroll
            for (int n = 0; n < 4; n++) {
                int kr = n * 16 + l15;
                bf16x8 b = *(const bf16x8*)(Ks + kr * 128 + (kb ^ ((kr & 7) << 4)));
                s_acc[n] = __builtin_amdgcn_mfma_f32_16x16x32_bf16(a, b, s_acc[n], 0, 0, 0);
            }
        }
        __builtin_amdgcn_s_setprio(0);
        char* pw = Ps + w * 2048;
#pragma unroll
        for (int j = 0; j < 4; j++) {
            float s0 = s_acc[0][j] * 0.125f, s1 = s_acc[1][j] * 0.125f;
            float s2 = s_acc[2][j] * 0.125f, s3 = s_acc[3][j] * 0.125f;
            float tmax = fmaxf(fmaxf(s0, s1), fmaxf(s2, s3));
#pragma unroll
            for (int o = 1; o < 16; o <<= 1) tmax = fmaxf(tmax, __shfl_xor(tmax, o));
            float mnew = fmaxf(m_r[j], tmax);
            float resc = __expf(m_r[j] - mnew);
            float p0 = __expf(s0 - mnew), p1 = __expf(s1 - mnew);
            float p2 = __expf(s2 - mnew), p3 = __expf(s3 - mnew);
            float ps = p0 + p1 + p2 + p3;
#pragma unroll
            for (int o = 1; o < 16; o <<= 1) ps += __shfl_xor(ps, o);
            l_r[j] = l_r[j] * resc + ps;
            m_r[j] = mnew;
            accO[0][j] *= resc; accO[1][j] *= resc;
            accO[2][j] *= resc; accO[3][j] *= resc;
            int prow = l16 * 4 + j;
            int sw = (prow & 7) << 4;
            *(unsigned short*)(pw + prow * 128 + ((2 * l15) ^ sw)) = f2bf(p0);
            *(unsigned short*)(pw + prow * 128 + ((2 * l15 + 32) ^ sw)) = f2bf(p1);
            *(unsigned short*)(pw + prow * 128 + ((2 * l15 + 64) ^ sw)) = f2bf(p2);
            *(unsigned short*)(pw + prow * 128 + ((2 * l15 + 96) ^ sw)) = f2bf(p3);
        }
        __builtin_amdgcn_s_setprio(1);
#pragma unroll
        for (int st = 0; st < 2; st++) {
            int kb = st * 64 + l16 * 16;
            bf16x8 pa = *(const bf16x8*)(pw + l15 * 128 + (kb ^ ((l15 & 7) << 4)));
#pragma unroll
            for (int n = 0; n < 4; n++) {
                int vr = n * 16 + l15;
                bf16x8 vb = *(const bf16x8*)(Vs + vr * 128 + (kb ^ ((vr & 7) << 4)));
                accO[n] = __builtin_amdgcn_mfma_f32_16x16x32_bf16(pa, vb, accO[n], 0, 0, 0);
            }
        }
        __builtin_amdgcn_s_setprio(0);
    }
    unsigned short* obase = O + (size_t)(bb * SEQ + qt * QBLK + w * 16) * DMODEL + hh * 64;
#pragma unroll
    for (int j = 0; j < 4; j++) {
        float inv = 1.f / l_r[j];
        int row = l16 * 4 + j;
#pragma unroll
        for (int n = 0; n < 4; n++)
            obase[(size_t)row * DMODEL + n * 16 + l15] = f2bf(accO[n][j] * inv);
    }
}

// ---------------- attention kernel + optional w1/ws1 riders (layer 0) ----------------
template <int RIDER>
__global__ __launch_bounds__(256, 2) void attn_kernel(
    const unsigned short* __restrict__ QKV, const unsigned short* __restrict__ Vt,
    unsigned short* __restrict__ O,
    const float* __restrict__ w1src, const float* __restrict__ ws1src,
    unsigned short* __restrict__ w1t, unsigned short* __restrict__ ws1t) {
    __shared__ char lds[32768];
    unsigned int bid = blockIdx.x;
    if (bid < 512) {
        attn_body(lds, bid, QKV, Vt, O);
    } else if (RIDER == 0) {
        unsigned int eb = bid - 512;
        if (eb < 2048) {
            int e = eb >> 6, tt = eb & 63;
            wt_tile_body(lds, w1src + (size_t)e * DDU, w1t + (size_t)e * DDU,
                         512, 512, tt & 7, tt >> 3);
        } else {
            int t = eb - 2048;
            wt_tile_body(lds, ws1src, ws1t, 512, 4096, t & 63, t >> 6);
        }
    }
}

// ---------------- O-proj kernel (flat, SK=2) + optional w2/ws2 riders (layer 0) ----------------
template <int RIDER>
__global__ __launch_bounds__(256, 2) void op_kernel(
    const unsigned short* __restrict__ t1b, const unsigned short* __restrict__ wot,
    float* __restrict__ pbuf,
    const float* __restrict__ w2src, const float* __restrict__ ws2src,
    unsigned short* __restrict__ w2t, unsigned short* __restrict__ ws2t) {
    __shared__ char lds[24576];
    unsigned int bid = blockIdx.x;
    if (bid < 512) {
        gemm_body<false, false, false, false, 2>(
            lds, lds + 16384, bid & 255, 8, 256, bid >> 8,
            t1b, wot, nullptr, pbuf, NTOK, DMODEL, DMODEL, nullptr, nullptr, nullptr, nullptr);
    } else if (RIDER == 0) {
        unsigned int eb = bid - 512;
        if (eb < 2048) {
            int e = eb >> 6, tt = eb & 63;
            wt_tile_body(lds, w2src + (size_t)e * DDU, w2t + (size_t)e * DDU,
                         512, 512, tt & 7, tt >> 3);
        } else {
            int t = eb - 2048;
            wt_tile_body(lds, ws2src, ws2t, 4096, 512, t & 7, t >> 3);
        }
    }
}

// ---------------- fused MLP stage 1 (+next-layer qkv/o transposes, biaspack, rdru) ----------------
__global__ __launch_bounds__(256, 2) void mlp1_kernel(
    const unsigned short* __restrict__ hb,
    const unsigned short* __restrict__ ws1t, const float* __restrict__ bs1,
    unsigned short* __restrict__ hidb,
    const unsigned short* __restrict__ w1t, const float* __restrict__ b1,
    unsigned short* __restrict__ ehid,
    const int* __restrict__ perm, const int* __restrict__ cnt,
    const int* __restrict__ poff, const int* __restrict__ tinfo,
    const float* __restrict__ nwq, const float* __restrict__ nwk,
    const float* __restrict__ nwv, const float* __restrict__ nwo,
    const float* __restrict__ nbq, const float* __restrict__ nbk, const float* __restrict__ nbv,
    unsigned short* __restrict__ wqkvt, unsigned short* __restrict__ wot,
    float* __restrict__ bqkv,
    const float* __restrict__ nrdw, const float* __restrict__ nruw, float* __restrict__ rdru) {
    __shared__ char lds[24576];
    unsigned int bid = blockIdx.x;
    if (bid < 2048) {
        gemm_body<true, false, false, true, 1>(
            lds, lds + 16384, bid, 64, 2048, 0,
            hb, ws1t, bs1, hidb, NTOK, HSHARED, DMODEL, nullptr, nullptr, nullptr, nullptr);
    } else if (bid < 3328) {
        gemm_body<true, true, true, true, 1>(
            lds, lds + 16384, bid - 2048, 8, 1280, 0,
            hb, w1t, b1, ehid, 0, HEXP, DMODEL, perm, cnt, poff, tinfo);
    } else {
        unsigned int eb = bid - 3328;
        if (eb < 256) {
            int w = eb >> 6, t = eb & 63;
            const float* src; unsigned short* dst;
            if (w == 0)      { src = nwq; dst = wqkvt; }
            else if (w == 1) { src = nwk; dst = wqkvt + DDU; }
            else if (w == 2) { src = nwv; dst = wqkvt + 2 * (size_t)DDU; }
            else             { src = nwo; dst = wot; }
            wt_tile_body(lds, src, dst, 512, 512, t & 7, t >> 3);
        } else if (eb < 262) {
            int i = (eb - 256) * 256 + threadIdx.x;
            float val = (i < 512) ? nbq[i] : (i < 1024 ? nbk[i - 512] : nbv[i - 1024]);
            bqkv[i] = val;
        } else {
            rdru_tile_body(lds, nrdw, nruw, rdru, (eb - 262) * 64);
        }
    }
}

// ---------------- fused MLP stage 2: shared FFN2 SK=2 || expert FFN2 (+next-layer w1/ws1 transposes) ----------------
__global__ __launch_bounds__(256, 2) void mlp2_kernel(
    const unsigned short* __restrict__ hidb,
    const unsigned short* __restrict__ ws2t, float* __restrict__ pbuf,
    const unsigned short* __restrict__ ehid,
    const unsigned short* __restrict__ w2t, const float* __restrict__ b2,
    unsigned short* __restrict__ eogb,
    const int* __restrict__ cnt, const int* __restrict__ poff,
    const int* __restrict__ tinfo,
    const float* __restrict__ nw1, const float* __restrict__ nws1,
    unsigned short* __restrict__ w1t, unsigned short* __restrict__ ws1t) {
    __shared__ char lds[24576];
    unsigned int bid = blockIdx.x;
    if (bid < 512) {
        int zidx = bid >> 8;                 // 2 z-planes of 256 blocks (8x32)
        gemm_body<false, false, false, false, 2>(
            lds, lds + 16384, bid & 255, 8, 256, zidx,
            hidb, ws2t, nullptr, pbuf, NTOK, DMODEL, HSHARED, nullptr, nullptr, nullptr, nullptr);
    } else if (bid < 1792) {
        gemm_body<false, false, true, true, 1>(
            lds, lds + 16384, bid - 512, 8, 1280, 0,
            ehid, w2t, b2, eogb, 0, DMODEL, HEXP, nullptr, cnt, poff, tinfo);
    } else {
        unsigned int eb = bid - 1792;
        if (eb < 2048) {
            int e = eb >> 6, tt = eb & 63;
            wt_tile_body(lds, nw1 + (size_t)e * DDU, w1t + (size_t)e * DDU,
                         512, 512, tt & 7, tt >> 3);
        } else {
            int t = eb - 2048;
            wt_tile_body(lds, nws1, ws1t, 512, 4096, t & 63, t >> 6);
        }
    }
}

// ---------------- router: shuffle-reduced stats + LAST-BLOCK scanaux fold ----------------
__global__ __launch_bounds__(256) void router_topk(const float* __restrict__ rsc,
                                                   float* __restrict__ topw,
                                                   int* __restrict__ topi,
                                                   int* __restrict__ cnt,
                                                   float* __restrict__ sumP,
                                                   float* __restrict__ zacc,
                                                   int* __restrict__ done,
                                                   int* __restrict__ poff,
                                                   int* __restrict__ tinfo,
                                                   int* __restrict__ perm,
                                                   float* __restrict__ out_aux, int l) {
    __shared__ float wP[4][NEXP];
    __shared__ int wC[4][NEXP];
    __shared__ float wZ[4];
    __shared__ int amLast;
    int tid = threadIdx.x;
    int wv = tid >> 6, lane = tid & 63;
    int n = blockIdx.x * 256 + tid;
    float sc[NEXP];
    float mx = -1e30f;
#pragma unroll
    for (int e = 0; e < NEXP; e++) { sc[e] = rsc[n * NEXP + e]; mx = fmaxf(mx, sc[e]); }
    float se = 0.f;
#pragma unroll
    for (int e = 0; e < NEXP; e++) { sc[e] = expf(sc[e] - mx); se += sc[e]; }
    float invse = 1.f / se;
    float lse = mx + logf(se);
    float z = lse * lse;
#pragma unroll
    for (int o = 32; o; o >>= 1) z += __shfl_xor(z, o);
    if (lane == 0) wZ[wv] = z;
#pragma unroll
    for (int e = 0; e < NEXP; e++) {
        float pv = sc[e] * invse;
#pragma unroll
        for (int o = 32; o; o >>= 1) pv += __shfl_xor(pv, o);
        if (lane == 0) wP[wv][e] = pv;
    }
    float tv[TOPK]; int ti[TOPK];
#pragma unroll
    for (int k = 0; k < TOPK; k++) {
        float best = -1.f; int bi = 0;
#pragma unroll
        for (int e = 0; e < NEXP; e++) {
            if (sc[e] > best) { best = sc[e]; bi = e; }
        }
        tv[k] = best * invse; ti[k] = bi; sc[bi] = -1.f;
    }
    float s4 = tv[0] + tv[1] + tv[2] + tv[3];
#pragma unroll
    for (int k = 0; k < TOPK; k++) {
        topw[n * TOPK + k] = tv[k] / s4;
        topi[n * TOPK + k] = ti[k];
    }
#pragma unroll
    for (int e = 0; e < NEXP; e++) {
        unsigned long long b0 = __ballot(ti[0] == e);
        unsigned long long b1 = __ballot(ti[1] == e);
        unsigned long long b2 = __ballot(ti[2] == e);
        unsigned long long b3 = __ballot(ti[3] == e);
        if (lane == 0)
            wC[wv][e] = __popcll(b0) + __popcll(b1) + __popcll(b2) + __popcll(b3);
    }
    __syncthreads();
    if (tid < NEXP) {
        atomicAdd(&sumP[tid], wP[0][tid] + wP[1][tid] + wP[2][tid] + wP[3][tid]);
        atomicAdd(&cnt[tid], wC[0][tid] + wC[1][tid] + wC[2][tid] + wC[3][tid]);
    }
    if (tid == 0) atomicAdd(zacc, wZ[0] + wZ[1] + wZ[2] + wZ[3]);
    // ---- last-block scanaux (no spinning: last arriver does the work) ----
    __syncthreads();
    __threadfence();
    if (tid == 0) amLast = (atomicAdd(done, 1) == (int)gridDim.x - 1);
    __syncthreads();
    if (amLast && tid < 64) {
        __threadfence();
        int laneid = tid;
        int c = (laneid < NEXP) ? atomicAdd(&cnt[laneid], 0) : 0;   // coherent read
        int nt = (c + 127) >> 7;
        int x = nt;
#pragma unroll
        for (int o = 1; o < 32; o <<= 1) {
            int y = __shfl_up(x, o);
            if (laneid >= o) x += y;
        }
        int excl = x - nt;
        if (laneid < NEXP) {
            poff[laneid] = excl * 128;
            for (int i = 0; i < nt; i++) {
                tinfo[1 + 2 * (excl + i)] = laneid;
                tinfo[2 + 2 * (excl + i)] = i * 128;
            }
            for (int i = c; i < nt * 128; i++) perm[excl * 128 + i] = 0;
        }
        float sp = (laneid < NEXP) ? atomicAdd(&sumP[laneid], 0.f) : 0.f;
        float lb = (laneid < NEXP) ? ((float)c / (float)NTOK) * (sp / (float)NTOK) : 0.f;
#pragma unroll
        for (int o = 32; o; o >>= 1) lb += __shfl_xor(lb, o);
        if (laneid == 31) {
            tinfo[0] = x;
            out_aux[l] = lb * (float)NEXP / (float)TOPK;
            out_aux[NLAYER + l] = atomicAdd(zacc, 0.f) / (float)NTOK;
        }
    }
}

// ---------------- scatter: LDS-aggregated per-block bases ----------------
__global__ __launch_bounds__(256) void scatter_kernel(const int* __restrict__ topi,
                                                      const int* __restrict__ poff,
                                                      int* __restrict__ cursor,
                                                      int* __restrict__ perm,
                                                      int* __restrict__ pos) {
    __shared__ int lcnt[NEXP];
    __shared__ int lbase[NEXP];
    if (threadIdx.x < NEXP) lcnt[threadIdx.x] = 0;
    __syncthreads();
    int i = blockIdx.x * 256 + threadIdx.x;
    int e = topi[i];
    int lr = atomicAdd(&lcnt[e], 1);
    __syncthreads();
    if (threadIdx.x < NEXP && lcnt[threadIdx.x] > 0)
        lbase[threadIdx.x] = atomicAdd(&cursor[threadIdx.x], lcnt[threadIdx.x]);
    __syncthreads();
    int g = poff[e] + lbase[e] + lr;
    perm[g] = i >> 2;
    pos[i] = g;
}

// ---------------- launcher ----------------
extern "C" void kernel_launch(void* const* d_in, const int* in_sizes, int n_in,
                              void* d_out, int out_size, void* d_ws, size_t ws_size,
                              hipStream_t stream) {
    (void)in_sizes; (void)n_in; (void)out_size; (void)ws_size;
    const float* x_in  = (const float*)d_in[0];
    const float* ln1_s = (const float*)d_in[1];
    const float* ln1_b = (const float*)d_in[2];
    const float* ln2_s = (const float*)d_in[3];
    const float* ln2_b = (const float*)d_in[4];
    const float* wq = (const float*)d_in[5];
    const float* bq = (const float*)d_in[6];
    const float* wk = (const float*)d_in[7];
    const float* bk = (const float*)d_in[8];
    const float* wv = (const float*)d_in[9];
    const float* bv = (const float*)d_in[10];
    const float* wo = (const float*)d_in[11];
    const float* bo = (const float*)d_in[12];
    const float* rdw = (const float*)d_in[13];
    const float* ruw = (const float*)d_in[14];
    const float* w1 = (const float*)d_in[15];
    const float* b1 = (const float*)d_in[16];
    const float* w2 = (const float*)d_in[17];
    const float* b2 = (const float*)d_in[18];
    const float* ws1 = (const float*)d_in[19];
    const float* bs1 = (const float*)d_in[20];
    const float* ws2 = (const float*)d_in[21];
    const float* bs2 = (const float*)d_in[22];
    const float* fn_s = (const float*)d_in[23];
    const float* fn_b = (const float*)d_in[24];

    float* ws = (float*)d_ws;
    const size_t ND = (size_t)NTOK * DMODEL;
    const size_t PADROWS = (size_t)MAXTILE * 128;
    size_t o = 0;
    float* xb  = ws + o; o += ND;
    unsigned short* hb     = (unsigned short*)(ws + o); o += ND / 2;
    unsigned short* qkv_bf = (unsigned short*)(ws + o); o += (size_t)NTOK * 1536 / 2;
    unsigned short* vT     = (unsigned short*)(ws + o); o += ND / 2;
    unsigned short* t1b    = (unsigned short*)(ws + o); o += ND / 2;
    unsigned short* hidb   = (unsigned short*)(ws + o); o += (size_t)NTOK * HSHARED / 2;
    unsigned short* ehid   = (unsigned short*)(ws + o); o += PADROWS * HEXP / 2;
    unsigned short* eogb   = (unsigned short*)(ws + o); o += PADROWS * DMODEL / 2;
    float* pbuf = ws + o; o += 4 * ND;                 // split-K partials (max SK=4)
    float* rdru = ws + o; o += (size_t)DMODEL * NEXP;
    float* rsc  = ws + o; o += (size_t)NTOK * NEXP;
    float* topw = ws + o; o += (size_t)NTOK * TOPK;
    float* bqkv = ws + o; o += 1536;
    int* topi = (int*)(ws + o); o += (size_t)NTOK * TOPK;
    int* pos  = (int*)(ws + o); o += (size_t)NTOK * TOPK;
    int* perm = (int*)(ws + o); o += PADROWS;
    int* stats = (int*)(ws + o); o += 256;
    int* tinfo = (int*)(ws + o); o += 512;
    int* cnt = stats;
    int* cursor = stats + 32;
    int* poff = stats + 64;
    float* sumP = (float*)(stats + 96);
    float* zacc = sumP + 32;
    int* done = stats + 129;         // zeroed with stats[0..160)
    unsigned short* wbf = (unsigned short*)(ws + o);
    unsigned short* wqkvt = wbf;
    unsigned short* wot  = wqkvt + 3 * (size_t)DDU;
    unsigned short* w1t  = wot + DDU;
    unsigned short* w2t  = w1t + (size_t)NEXP * DDU;
    unsigned short* ws1t = w2t + (size_t)NEXP * DDU;
    unsigned short* ws2t = ws1t + (size_t)DMODEL * HSHARED;

    float* out_x = (float*)d_out;
    float* out_aux = out_x + ND;

    hipMemcpyAsync(xb, x_in, ND * sizeof(float), hipMemcpyDeviceToDevice, stream);

    dim3 blk(256);

    for (int l = 0; l < NLAYER; l++) {
        const size_t DD = (size_t)DMODEL * DMODEL;
        bool hasNext = (l + 1 < NLAYER);
        int lnx = hasNext ? (l + 1) : l;
        if (l == 0) {
            prep0_kernel<<<1230, blk, 0, stream>>>(
                wq, wk, wv, bq, bk, bv, wqkvt, bqkv, stats,
                rdw, ruw, rdru, xb, ln1_s, ln1_b, hb);
            qkv_kernel<0><<<832, blk, 0, stream>>>(
                hb, wqkvt, bqkv, qkv_bf, vT, wo, nullptr, wot, nullptr, nullptr);
        } else {
            qkv_kernel<1><<<3329, blk, 0, stream>>>(
                hb, wqkvt, bqkv, qkv_bf, vT,
                w2 + (size_t)l * NEXP * DD, ws2 + (size_t)l * HSHARED * DMODEL,
                w2t, ws2t, stats);
        }
        // ---- attention (V pre-transposed by qkv epilogue; +layer-0: w1/ws1 transposes) ----
        if (l == 0)
            attn_kernel<0><<<3072, blk, 0, stream>>>(qkv_bf, vT, t1b, w1, ws1, w1t, ws1t);
        else
            attn_kernel<1><<<512, blk, 0, stream>>>(qkv_bf, vT, t1b, nullptr, nullptr, nullptr, nullptr);
        // ---- out proj SK=2 (+layer-0: w2/ws2 transposes) ----
        if (l == 0)
            op_kernel<0><<<3072, blk, 0, stream>>>(t1b, wot, pbuf, w2, ws2, w2t, ws2t);
        else
            op_kernel<1><<<512, blk, 0, stream>>>(t1b, wot, pbuf, nullptr, nullptr, nullptr, nullptr);
        // ---- fused reduce+LN2+router-scores ----
        reduceln_kernel<2, false, 1, true><<<NTOK / 4, blk, 0, stream>>>(
            pbuf, bo + l * DMODEL, nullptr, nullptr, nullptr, xb,
            ln2_s + l * DMODEL, ln2_b + l * DMODEL, nullptr, hb, rdru, rsc);
        // ---- router top-k + stats + last-block scanaux ----
        router_topk<<<NTOK / 256, blk, 0, stream>>>(
            rsc, topw, topi, cnt, sumP, zacc, done, poff, tinfo, perm, out_aux, l);
        scatter_kernel<<<NTOK * TOPK / 256, blk, 0, stream>>>(topi, poff, cursor, perm, pos);
        // ---- fused MLP stage 1 (+next-layer qkv/o transposes + biaspack + rdru) ----
        int ln1g = hasNext ? 3598 : 3328;
        mlp1_kernel<<<ln1g, blk, 0, stream>>>(
            hb, ws1t, bs1 + (size_t)l * HSHARED, hidb,
            w1t, b1 + (size_t)l * NEXP * HEXP, ehid,
            perm, cnt, poff, tinfo,
            wq + (size_t)lnx * DD, wk + (size_t)lnx * DD,
            wv + (size_t)lnx * DD, wo + (size_t)lnx * DD,
            bq + (size_t)lnx * DMODEL, bk + (size_t)lnx * DMODEL, bv + (size_t)lnx * DMODEL,
            wqkvt, wot, bqkv,
            rdw + (size_t)lnx * DMODEL * RRANK, ruw + (size_t)lnx * RRANK * NEXP, rdru);
        // ---- fused MLP stage 2: shared FFN2 SK=2 || expert FFN2 (+next-layer w1/ws1 transposes) ----
        int ln2g = hasNext ? 4352 : 1792;
        mlp2_kernel<<<ln2g, blk, 0, stream>>>(
            hidb, ws2t, pbuf,
            ehid, w2t, b2 + (size_t)l * NEXP * DMODEL, eogb,
            cnt, poff, tinfo,
            w1 + (size_t)lnx * NEXP * DD, ws1 + (size_t)lnx * DMODEL * HSHARED,
            w1t, ws1t);
        // ---- fused reduce+MoE-combine+LN (next layer or final) ----
        if (hasNext) {
            reduceln_kernel<2, true, 1, false><<<NTOK / 4, blk, 0, stream>>>(
                pbuf, bs2 + l * DMODEL, eogb, topw, pos, xb,
                ln1_s + (l + 1) * DMODEL, ln1_b + (l + 1) * DMODEL, nullptr, hb, nullptr, nullptr);
        } else {
            reduceln_kernel<2, true, 0, false><<<NTOK / 4, blk, 0, stream>>>(
                pbuf, bs2 + l * DMODEL, eogb, topw, pos, xb,
                fn_s, fn_b, out_x, nullptr, nullptr, nullptr);
        }
    }
}